// Round 3
// baseline (32706.070 us; speedup 1.0000x reference)
//
#include <hip/hip_runtime.h>
#include <hip/hip_cooperative_groups.h>

namespace cg = cooperative_groups;

// rnn_phy persistent-kernel R3.
// R2 failed with output==zeros => cooperative kernel never ran; prime suspect: 102KB static LDS
// (> 64KB per-workgroup limit). R3: every phase <= 64KB LDS (max 60,960B), plus a runtime
// fallback to per-phase kernel launches if hipLaunchCooperativeKernel returns an error.

#define Nn 512
#define Dd 130
#define DP 132
#define Hh 128
#define Ee 64
#define FFf 2048

struct Args {
  const float *Tracks, *W_emb, *b_emb, *W_ih, *W_hh, *b_ih, *b_hh;
  const float *qkv_w, *qkv_b, *out_w, *out_b, *ff1_w, *ff1_b, *ff2_w, *ff2_b;
  const float *ln1_s, *ln1_b, *ln2_s, *ln2_b;
  const float *W_sp, *b_sp, *W_p1, *b_p1, *W_p2, *b_p2, *W_pl, *b_pl;
  float *X, *T, *Q, *Kb, *V, *O, *Sh, *C, *X1, *X2, *PART;
  float *WgP, *qkvP, *outP, *ff1P, *ff2P, *WspP, *Wp1P, *Wp2P;
  float *outp;
};

__device__ __forceinline__ float sigm(float x){ return 1.f/(1.f+__expf(-x)); }
__device__ __forceinline__ float dot4(float4 a, float4 b){
  return a.x*b.x + a.y*b.y + a.z*b.z + a.w*b.w;
}

// ---- weight packing (grid-stride, 256 blocks x 256 threads) ----
__device__ void ph_pack(const Args& a){
  int gid = blockIdx.x*256 + threadIdx.x, gsz = 256*256;
  // WgP: [us 0..15][g 0..3][u_l 0..7][196]  (row-in-slice = g*8+u_l)
  for (int idx=gid; idx<128*4*196; idx+=gsz){
    int j = idx%196, row = idx/196;
    int us = row>>5, r5 = row&31, g = r5>>3, u_l = r5&7;
    int u = us*8 + u_l;
    float v = 0.f;
    if (j<64)       v = a.W_ih[(g*Hh+u)*Ee + j];
    else if (j<192) v = a.W_hh[(g*Hh+u)*Hh + (j-64)];
    a.WgP[idx] = v;
  }
  // qkvP: [3][448][132]
  for (int idx=gid; idx<3*448*132; idx+=gsz){
    int j = idx%132, row = (idx/132)%448, l = idx/(132*448);
    a.qkvP[idx] = (row<390 && j<130) ? a.qkv_w[(l*390+row)*130 + j] : 0.f;
  }
  // outP: [3][132][132]
  for (int idx=gid; idx<3*132*132; idx+=gsz){
    int j = idx%132, row = (idx/132)%132, l = idx/(132*132);
    a.outP[idx] = (row<130 && j<130) ? a.out_w[(l*130+row)*130 + j] : 0.f;
  }
  // ff1P: [3][2048][132]
  for (int idx=gid; idx<3*2048*132; idx+=gsz){
    int j = idx%132, row = (idx/132)%2048, l = idx/(132*2048);
    a.ff1P[idx] = (j<130) ? a.ff1_w[(l*2048+row)*130 + j] : 0.f;
  }
  // ff2P: [3][132][2048]
  for (int idx=gid; idx<3*132*2048; idx+=gsz){
    int k = idx%2048, c = (idx/2048)%132, l = idx/(2048*132);
    a.ff2P[idx] = (c<130) ? a.ff2_w[(l*130+c)*2048 + k] : 0.f;
  }
  // WspP [128][132], Wp1P/Wp2P [128][132]
  for (int idx=gid; idx<128*132; idx+=gsz){
    int j = idx%132, row = idx/132;
    a.WspP[idx] = (j<130) ? a.W_sp[row*130+j] : 0.f;
    a.Wp1P[idx] = (j<128) ? a.W_p1[row*128+j] : 0.f;
    a.Wp2P[idx] = (j<128) ? a.W_p2[row*128+j] : 0.f;
  }
}

// ---- generic 32x64 tile GEMM (strides 132) ----
__device__ __forceinline__ void tile_gemm_32x64(const float* xs, const float* ws, float acc[2][4]){
  int tid = threadIdx.x, cgi = tid&15, ig = tid>>4;
  #pragma unroll
  for (int r=0;r<2;r++)
    #pragma unroll
    for (int c=0;c<4;c++) acc[r][c]=0.f;
  for (int j4=0;j4<33;j4++){
    float4 xa[2], wv[4];
    #pragma unroll
    for (int r=0;r<2;r++) xa[r] = *(const float4*)(xs + (ig+16*r)*132 + j4*4);
    #pragma unroll
    for (int c=0;c<4;c++) wv[c] = *(const float4*)(ws + (cgi+16*c)*132 + j4*4);
    #pragma unroll
    for (int r=0;r<2;r++)
      #pragma unroll
      for (int c=0;c<4;c++) acc[r][c] += dot4(xa[r], wv[c]);
  }
}

// ---- proj: Sh = X@Wsp^T + b_sp (512x128). blocks < 32 (16 rowg x 2 colg) ----
__device__ void ph_proj(const Args& a, float* sm, int b){
  if (b>=32) return;
  int rg = b>>1, cs = b&1, r0 = rg*32, c0 = cs*64;
  float* xs = sm; float* wsl = sm + 4224;
  int tid = threadIdx.x;
  for (int idx=tid; idx<32*33; idx+=256)
    ((float4*)xs)[idx] = ((const float4*)(a.X + r0*DP))[idx];
  for (int idx=tid; idx<64*33; idx+=256)
    ((float4*)wsl)[idx] = ((const float4*)(a.WspP + c0*132))[idx];
  __syncthreads();
  float acc[2][4];
  tile_gemm_32x64(xs, wsl, acc);
  int cgi = tid&15, ig = tid>>4;
  #pragma unroll
  for (int r=0;r<2;r++)
    #pragma unroll
    for (int c=0;c<4;c++){
      int rr = r0+ig+16*r, cc = c0+cgi+16*c;
      a.Sh[rr*Hh+cc] = acc[r][c] + a.b_sp[cc];
    }
  __syncthreads();
}

// ---- mlp: out = relu(in@W^T+b)+in (512x128, K=128). blocks < 32 ----
__device__ void ph_mlp(const Args& a, float* sm, int b, const float* inp, const float* WP, const float* bias, float* outp){
  if (b>=32) return;
  int rg = b>>1, cs = b&1, r0 = rg*32, c0 = cs*64;
  float* xs = sm; float* wsl = sm + 4224;
  int tid = threadIdx.x;
  for (int idx=tid; idx<32*32; idx+=256){ int i=idx>>5, k=idx&31;
    ((float4*)(xs+i*132))[k] = ((const float4*)(inp+(r0+i)*Hh))[k]; }
  if (tid<32) *(float4*)(xs + tid*132 + 128) = float4{0.f,0.f,0.f,0.f};
  for (int idx=tid; idx<64*33; idx+=256)
    ((float4*)wsl)[idx] = ((const float4*)(WP + c0*132))[idx];
  __syncthreads();
  float acc[2][4];
  tile_gemm_32x64(xs, wsl, acc);
  int cgi = tid&15, ig = tid>>4;
  #pragma unroll
  for (int r=0;r<2;r++)
    #pragma unroll
    for (int c=0;c<4;c++){
      int rr = r0+ig+16*r, cc = c0+cgi+16*c;
      outp[rr*Hh+cc] = fmaxf(acc[r][c] + bias[cc], 0.f) + inp[rr*Hh+cc];
    }
  __syncthreads();
}

// ---- gates: emb + LSTM fused. 256 blocks = 16 rowg(32) x 16 unit-slices(8) ----
__device__ void ph_gates(const Args& a, float* sm, int b, int xin_mode, int tstep, int p, int sh_zero){
  int rg = b&15, us = b>>4;
  int r0 = rg*32, u0 = us*8;
  float* xs  = sm;           // 32 x 196
  float* wsg = sm + 6272;    // 32 x 196 (rows = g*8+u_l)
  float* xin = sm + 12544;   // 32 x 4
  int tid = threadIdx.x;
  for (int idx=tid; idx<32*4; idx+=256){ int i=idx>>2, j=idx&3; int r=r0+i;
    xin[idx] = (xin_mode==0) ? a.Tracks[(r*20+tstep)*5+1+j] : a.outp[r*40+p*4+j]; }
  for (int idx=tid; idx<32*32; idx+=256){ int i=idx>>5, k=idx&31;
    ((float4*)(xs + i*196 + 64))[k] = sh_zero ? float4{0.f,0.f,0.f,0.f}
                                              : ((const float4*)(a.Sh + (r0+i)*Hh))[k]; }
  if (tid<32) *(float4*)(xs + tid*196 + 192) = float4{0.f,0.f,0.f,0.f};
  for (int idx=tid; idx<32*49; idx+=256)
    ((float4*)wsg)[idx] = ((const float4*)(a.WgP + us*32*196))[idx];
  __syncthreads();
  for (int idx=tid; idx<32*Ee; idx+=256){ int i=idx>>6, e=idx&63;
    float s = a.b_emb[e];
    #pragma unroll
    for (int j=0;j<4;j++) s += xin[i*4+j]*a.W_emb[e*4+j];
    xs[i*196+e] = s; }
  __syncthreads();
  int u_l = tid&7, row = tid>>3;
  float acc[4] = {0.f,0.f,0.f,0.f};
  for (int j4=0;j4<49;j4++){
    float4 xa = *(const float4*)(xs + row*196 + j4*4);
    #pragma unroll
    for (int g=0; g<4; g++){
      float4 wv = *(const float4*)(wsg + (g*8+u_l)*196 + j4*4);
      acc[g] += dot4(xa, wv);
    }
  }
  int u = u0 + u_l, rr = r0 + row;
  float gi = acc[0] + a.b_ih[u]      + a.b_hh[u];
  float gf = acc[1] + a.b_ih[Hh+u]   + a.b_hh[Hh+u];
  float gg = acc[2] + a.b_ih[2*Hh+u] + a.b_hh[2*Hh+u];
  float go = acc[3] + a.b_ih[3*Hh+u] + a.b_hh[3*Hh+u];
  float cp = sh_zero ? 0.f : a.C[rr*Hh+u];
  float c2 = sigm(gf)*cp + sigm(gi)*tanhf(gg);
  a.C[rr*Hh+u] = c2;
  a.X[rr*DP+u] = sigm(go)*tanhf(c2);
  if (us==0){
    if (u_l<2)      a.X[rr*DP + Hh + u_l]      = xin[row*4+u_l];
    else if (u_l<4) a.X[rr*DP + 130 + (u_l-2)] = 0.f;
  }
  __syncthreads();
}

// ---- qkv: 512x390. blocks < 112 (16 rowg x 7 colg) ----
__device__ void ph_qkv(const Args& a, float* sm, int b, int l){
  if (b>=112) return;
  int rg = b/7, cs = b%7, r0 = rg*32, c0 = cs*64;
  float* xs = sm; float* wsl = sm + 4224;
  int tid = threadIdx.x;
  for (int idx=tid; idx<32*33; idx+=256)
    ((float4*)xs)[idx] = ((const float4*)(a.X + r0*DP))[idx];
  for (int idx=tid; idx<64*33; idx+=256)
    ((float4*)wsl)[idx] = ((const float4*)(a.qkvP + (l*448 + c0)*132))[idx];
  __syncthreads();
  float acc[2][4];
  tile_gemm_32x64(xs, wsl, acc);
  int cgi = tid&15, ig = tid>>4;
  const float* qb = a.qkv_b + l*390;
  #pragma unroll
  for (int r=0;r<2;r++)
    #pragma unroll
    for (int c=0;c<4;c++){
      int cc = c0+cgi+16*c;
      if (cc < 390){
        int rr = r0+ig+16*r;
        float v = acc[r][c] + qb[cc];
        if (cc < Dd)        a.Q [rr*DP + cc]        = v;
        else if (cc < 2*Dd) a.Kb[rr*DP + (cc-Dd)]   = v;
        else                a.V [rr*DP + (cc-2*Dd)] = v;
      }
    }
  __syncthreads();
}

// ---- attention: 320 items (16-row tile x head); scores/softmax in registers ----
__device__ void ph_attn(const Args& a, float* sm, int b){
  float* kv = sm;   // 512 x 20
  int tid = threadIdx.x;
  const float scale = rsqrtf(13.f);
  int mg = tid&15, ii = tid>>4;
  for (int item=b; item<320; item+=256){
    int tile = item&31, head = item>>5;
    int r0 = tile*16, hc = head*13;
    __syncthreads();
    for (int idx=tid; idx<512*13; idx+=256){ int m=idx/13, d=idx-13*m; kv[m*20+d]=a.Kb[m*DP+hc+d]; }
    __syncthreads();
    float q[13];
    #pragma unroll
    for (int d=0;d<13;d++) q[d] = a.Q[(r0+ii)*DP+hc+d]*scale;
    float4 q0={q[0],q[1],q[2],q[3]}, q1={q[4],q[5],q[6],q[7]}, q2={q[8],q[9],q[10],q[11]};
    float s[32], mx = -1e30f;
    #pragma unroll
    for (int k=0;k<32;k++){
      const float* kr = kv + (mg+16*k)*20;
      float v = dot4(q0,*(const float4*)kr) + dot4(q1,*(const float4*)(kr+4))
              + dot4(q2,*(const float4*)(kr+8)) + q[12]*kr[12];
      s[k]=v; mx=fmaxf(mx,v);
    }
    #pragma unroll
    for (int o=8;o>=1;o>>=1) mx = fmaxf(mx, __shfl_xor(mx,o,16));
    float sum = 0.f;
    #pragma unroll
    for (int k=0;k<32;k++){ s[k]=__expf(s[k]-mx); sum+=s[k]; }
    #pragma unroll
    for (int o=8;o>=1;o>>=1) sum += __shfl_xor(sum,o,16);
    float inv = 1.f/sum;
    __syncthreads();
    for (int idx=tid; idx<512*13; idx+=256){ int m=idx/13, d=idx-13*m; kv[m*20+d]=a.V[m*DP+hc+d]; }
    __syncthreads();
    float o_[13];
    #pragma unroll
    for (int d=0;d<13;d++) o_[d]=0.f;
    #pragma unroll
    for (int k=0;k<32;k++){
      const float* vr = kv + (mg+16*k)*20;
      float p = s[k];
      float4 v0=*(const float4*)vr, v1=*(const float4*)(vr+4), v2=*(const float4*)(vr+8);
      o_[0]+=p*v0.x; o_[1]+=p*v0.y; o_[2] +=p*v0.z; o_[3] +=p*v0.w;
      o_[4]+=p*v1.x; o_[5]+=p*v1.y; o_[6] +=p*v1.z; o_[7] +=p*v1.w;
      o_[8]+=p*v2.x; o_[9]+=p*v2.y; o_[10]+=p*v2.z; o_[11]+=p*v2.w;
      o_[12]+=p*vr[12];
    }
    #pragma unroll
    for (int d=0;d<13;d++){
      #pragma unroll
      for (int o=8;o>=1;o>>=1) o_[d] += __shfl_xor(o_[d],o,16);
    }
    float outv = 0.f;
    #pragma unroll
    for (int d=0;d<13;d++) if (mg==d) outv = o_[d];
    if (mg<13) a.O[(r0+ii)*DP+hc+mg] = outv*inv;
  }
  __syncthreads();
}

// ---- oproj + residual: T = O@ow^T + ob + X. blocks < 32 (16 rowg x 2 colg of 65) ----
__device__ void ph_oproj(const Args& a, float* sm, int b, int l){
  if (b>=32) return;
  int rg = b>>1, cs = b&1, r0 = rg*32, c0 = cs*65;
  float* xs = sm; float* wsl = sm + 4224;  // 66 x 132
  int tid = threadIdx.x;
  for (int idx=tid; idx<32*33; idx+=256)
    ((float4*)xs)[idx] = ((const float4*)(a.O + r0*DP))[idx];
  for (int idx=tid; idx<66*33; idx+=256)
    ((float4*)wsl)[idx] = ((const float4*)(a.outP + (l*132 + c0)*132))[idx];
  __syncthreads();
  int cgi = tid&15, ig = tid>>4;
  float acc[2][5];
  #pragma unroll
  for (int r=0;r<2;r++)
    #pragma unroll
    for (int c=0;c<5;c++) acc[r][c]=0.f;
  for (int j4=0;j4<33;j4++){
    float4 xa[2], wv[5];
    #pragma unroll
    for (int r=0;r<2;r++) xa[r] = *(const float4*)(xs + (ig+16*r)*132 + j4*4);
    #pragma unroll
    for (int c=0;c<5;c++){ int crow = cgi+16*c; crow = crow>65?65:crow;
      wv[c] = *(const float4*)(wsl + crow*132 + j4*4); }
    #pragma unroll
    for (int r=0;r<2;r++)
      #pragma unroll
      for (int c=0;c<5;c++) acc[r][c] += dot4(xa[r], wv[c]);
  }
  const float* ob = a.out_b + l*Dd;
  #pragma unroll
  for (int r=0;r<2;r++)
    #pragma unroll
    for (int c=0;c<5;c++){
      int cl = cgi+16*c, cc = c0+cl;
      if (cl<65 && cc<Dd){
        int rr = r0+ig+16*r;
        a.T[rr*DP+cc] = acc[r][c] + ob[cc] + a.X[rr*DP+cc];
      }
    }
  __syncthreads();
}

// ---- layernorm: blocks < 64, 8 rows each. mode_ff=1 sums PART slices ----
__device__ void ph_ln(const Args& a, float* sm, int b, const float* s, const float* bv, int mode_ff, int l){
  if (b>=64) return;
  int r0 = b*8;
  float* row  = sm;          // 8 x 132
  float* red1 = sm + 1056;   // 8 x 33
  float* red2 = sm + 1320;
  float* mu   = sm + 1584;
  float* inv  = sm + 1592;
  int tid = threadIdx.x, i = tid>>5, l5 = tid&31;
  if (mode_ff==0){
    for (int idx=tid; idx<8*Dd; idx+=256){ int ii=idx/Dd, c=idx-ii*Dd; row[ii*132+c]=a.T[(r0+ii)*DP+c]; }
  } else {
    const float* f2b = a.ff2_b + l*Dd;
    for (int idx=tid; idx<8*Dd; idx+=256){ int ii=idx/Dd, c=idx-ii*Dd;
      float sum = a.X[(r0+ii)*DP+c] + f2b[c];
      for (int ksl=0;ksl<16;ksl++) sum += a.PART[(ksl*Nn + r0+ii)*DP + c];
      row[ii*132+c]=sum; }
  }
  __syncthreads();
  { float s1=0.f, s2=0.f;
    for (int k=0;k<5;k++){ int c=l5+32*k; if(c<Dd){ float v=row[i*132+c]; s1+=v; s2+=v*v; } }
    red1[i*33+l5]=s1; red2[i*33+l5]=s2; }
  __syncthreads();
  if (tid<8){ float s1=0.f,s2=0.f; for(int k=0;k<32;k++){ s1+=red1[tid*33+k]; s2+=red2[tid*33+k]; }
    float m=s1/130.f; mu[tid]=m; inv[tid]=rsqrtf(s2/130.f - m*m + 1e-5f); }
  __syncthreads();
  for (int idx=tid; idx<8*Dd; idx+=256){ int ii=idx/Dd, c=idx-ii*Dd;
    a.X[(r0+ii)*DP+c] = (row[ii*132+c]-mu[ii])*inv[ii]*s[c] + bv[c]; }
  __syncthreads();
}

// ---- fused FF1+FF2: 256 blocks = 16 rowg(32) x 16 k-slices(128); 2 sub-slices of 64 ----
__device__ void ph_ff(const Args& a, float* sm, int b, int l){
  int rg = b&15, ksl = b>>4, r0 = rg*32, k0 = ksl*128;
  float* xs  = sm;          // 32 x 132
  float* ys  = sm + 4224;   // 32 x 68
  float* wsh = sm + 6400;   // max(64x132, 130x68) = 8840
  int tid = threadIdx.x, cgi = tid&15, ig = tid>>4;
  for (int idx=tid; idx<32*33; idx+=256)
    ((float4*)xs)[idx] = ((const float4*)(a.X + r0*DP))[idx];
  float acc2[2][9];
  #pragma unroll
  for (int r=0;r<2;r++)
    #pragma unroll
    for (int c=0;c<9;c++) acc2[r][c]=0.f;
  for (int sub=0; sub<2; sub++){
    int ks0 = k0 + sub*64;
    __syncthreads();
    for (int idx=tid; idx<64*33; idx+=256)
      ((float4*)wsh)[idx] = ((const float4*)(a.ff1P + (l*2048 + ks0)*132))[idx];
    __syncthreads();
    // GEMM1: ys(32x64) = relu(X @ W1slice^T + b1)
    float acc[2][4];
    #pragma unroll
    for (int r=0;r<2;r++)
      #pragma unroll
      for (int c=0;c<4;c++) acc[r][c]=0.f;
    for (int j4=0;j4<33;j4++){
      float4 xa[2], wv[4];
      #pragma unroll
      for (int r=0;r<2;r++) xa[r] = *(const float4*)(xs + (ig+16*r)*132 + j4*4);
      #pragma unroll
      for (int c=0;c<4;c++) wv[c] = *(const float4*)(wsh + (cgi+16*c)*132 + j4*4);
      #pragma unroll
      for (int r=0;r<2;r++)
        #pragma unroll
        for (int c=0;c<4;c++) acc[r][c] += dot4(xa[r], wv[c]);
    }
    const float* b1 = a.ff1_b + l*FFf + ks0;
    #pragma unroll
    for (int r=0;r<2;r++)
      #pragma unroll
      for (int c=0;c<4;c++){
        int lc = cgi+16*c;
        ys[(ig+16*r)*68 + lc] = fmaxf(acc[r][c] + b1[lc], 0.f);
      }
    __syncthreads();
    // stage W2 slice [130][64] stride 68
    for (int idx=tid; idx<130*16; idx+=256){ int c=idx>>4, kk=idx&15;
      ((float4*)(wsh + c*68))[kk] = ((const float4*)(a.ff2P + (l*132+c)*2048 + ks0))[kk]; }
    __syncthreads();
    // GEMM2 accumulate: acc2 += Ytile @ W2slice^T
    for (int j4=0;j4<16;j4++){
      float4 ya[2], wv[9];
      #pragma unroll
      for (int r=0;r<2;r++) ya[r] = *(const float4*)(ys + (ig+16*r)*68 + j4*4);
      #pragma unroll
      for (int c=0;c<9;c++){ int crow = cgi+16*c; crow = crow>129?129:crow;
        wv[c] = *(const float4*)(wsh + crow*68 + j4*4); }
      #pragma unroll
      for (int r=0;r<2;r++)
        #pragma unroll
        for (int c=0;c<9;c++) acc2[r][c] += dot4(ya[r], wv[c]);
    }
  }
  #pragma unroll
  for (int r=0;r<2;r++)
    #pragma unroll
    for (int c=0;c<9;c++){
      int cc = cgi+16*c;
      if (cc < Dd){
        int rr = r0+ig+16*r;
        a.PART[(ksl*Nn + rr)*DP + cc] = acc2[r][c];
      }
    }
  __syncthreads();
}

// ---- pred head ----
__device__ void ph_pout(const Args& a, float* sm, int b, int p){
  if (b>=64) return;
  int r0 = b*8;
  float* red = sm;  // 16 x 17
  int tid = threadIdx.x;
  int o = tid & 15, kq = tid >> 4;
  int ii = o>>1, jj = o&1, r = r0+ii;
  float s = 0.f;
  for (int v=kq*8; v<kq*8+8; v++) s += a.X2[r*Hh+v]*a.W_pl[jj*Hh+v];
  red[o*17+kq] = s;
  __syncthreads();
  if (tid < 16){
    int oo=tid, i2=oo>>1, j=oo&1, rr=r0+i2;
    float av = a.b_pl[j];
    for (int k=0;k<16;k++) av += red[oo*17+k];
    float cf0, cf2;
    if (p==0){ cf0 = a.Tracks[(rr*20+19)*5+1+j]; cf2 = a.Tracks[(rr*20+19)*5+3+j]; }
    else     { cf0 = a.outp[rr*40+(p-1)*4+j];    cf2 = a.outp[rr*40+(p-1)*4+2+j]; }
    float vv = av*0.1f + cf2;
    float pn = av*0.005f + vv*0.1f + cf0;
    a.outp[rr*40+p*4+j]   = pn;
    a.outp[rr*40+p*4+2+j] = vv;
  }
  __syncthreads();
}

// ================= persistent cooperative kernel =================
__global__ void __launch_bounds__(256, 1) persist(Args a){
  cg::grid_group grid = cg::this_grid();
  __shared__ float sm[15240];   // 60,960 B  (<= 64KB)
  int b = blockIdx.x;

  ph_pack(a);
  grid.sync();

  auto enc = [&](){
    for (int l=0;l<3;l++){
      ph_qkv(a, sm, b, l);                                grid.sync();
      ph_attn(a, sm, b);                                  grid.sync();
      ph_oproj(a, sm, b, l);                              grid.sync();
      ph_ln(a, sm, b, a.ln1_s+l*Dd, a.ln1_b+l*Dd, 0, l);  grid.sync();
      ph_ff(a, sm, b, l);                                 grid.sync();
      ph_ln(a, sm, b, a.ln2_s+l*Dd, a.ln2_b+l*Dd, 1, l);  grid.sync();
    }
  };

  ph_gates(a, sm, b, 0, 0, 0, 1);  grid.sync();
  enc();
  for (int t=0;t<20;t++){
    ph_proj(a, sm, b);               grid.sync();
    ph_gates(a, sm, b, 0, t, 0, 0);  grid.sync();
    enc();
  }
  for (int p=0;p<10;p++){
    ph_proj(a, sm, b);                              grid.sync();
    ph_mlp(a, sm, b, a.Sh, a.Wp1P, a.b_p1, a.X1);   grid.sync();
    ph_mlp(a, sm, b, a.X1, a.Wp2P, a.b_p2, a.X2);   grid.sync();
    ph_pout(a, sm, b, p);                           grid.sync();
    if (p < 9){
      ph_gates(a, sm, b, 1, 0, p, 0);               grid.sync();
      enc();
    }
  }
}

// ================= fallback per-phase kernels =================
__global__ __launch_bounds__(256) void g_pack(Args a){ ph_pack(a); }
__global__ __launch_bounds__(256) void g_proj(Args a){ __shared__ float sm[12672]; ph_proj(a, sm, blockIdx.x); }
__global__ __launch_bounds__(256) void g_mlp(Args a, const float* inp, const float* WP, const float* bias, float* outp){
  __shared__ float sm[12672]; ph_mlp(a, sm, blockIdx.x, inp, WP, bias, outp); }
__global__ __launch_bounds__(256) void g_gates(Args a, int m, int t, int p, int z){
  __shared__ float sm[12676]; ph_gates(a, sm, blockIdx.x, m, t, p, z); }
__global__ __launch_bounds__(256) void g_qkv(Args a, int l){ __shared__ float sm[12672]; ph_qkv(a, sm, blockIdx.x, l); }
__global__ __launch_bounds__(256) void g_attn(Args a){ __shared__ float sm[10240]; ph_attn(a, sm, blockIdx.x); }
__global__ __launch_bounds__(256) void g_oproj(Args a, int l){ __shared__ float sm[12936]; ph_oproj(a, sm, blockIdx.x, l); }
__global__ __launch_bounds__(256) void g_ln(Args a, const float* s, const float* bv, int m, int l){
  __shared__ float sm[1600]; ph_ln(a, sm, blockIdx.x, s, bv, m, l); }
__global__ __launch_bounds__(256) void g_ff(Args a, int l){ __shared__ float sm[15240]; ph_ff(a, sm, blockIdx.x, l); }
__global__ __launch_bounds__(256) void g_pout(Args a, int p){ __shared__ float sm[272]; ph_pout(a, sm, blockIdx.x, p); }

extern "C" void kernel_launch(void* const* d_in, const int* in_sizes, int n_in,
                              void* d_out, int out_size, void* d_ws, size_t ws_size,
                              hipStream_t stream) {
  (void)in_sizes; (void)n_in; (void)out_size; (void)ws_size;
  Args A;
  const float* const* in = (const float* const*)d_in;
  A.Tracks=in[0]; A.W_emb=in[1]; A.b_emb=in[2]; A.W_ih=in[3]; A.W_hh=in[4]; A.b_ih=in[5]; A.b_hh=in[6];
  A.qkv_w=in[7]; A.qkv_b=in[8]; A.out_w=in[9]; A.out_b=in[10];
  A.ff1_w=in[11]; A.ff1_b=in[12]; A.ff2_w=in[13]; A.ff2_b=in[14];
  A.ln1_s=in[15]; A.ln1_b=in[16]; A.ln2_s=in[17]; A.ln2_b=in[18];
  A.W_sp=in[19]; A.b_sp=in[20]; A.W_p1=in[21]; A.b_p1=in[22]; A.W_p2=in[23]; A.b_p2=in[24];
  A.W_pl=in[25]; A.b_pl=in[26];
  float* ws = (float*)d_ws;
  A.X    = ws;
  A.T    = ws + 67584;
  A.Q    = ws + 135168;
  A.Kb   = ws + 202752;
  A.V    = ws + 270336;
  A.O    = ws + 337920;
  A.Sh   = ws + 405504;
  A.C    = ws + 471040;
  A.X1   = ws + 536576;
  A.X2   = ws + 602112;
  A.PART = ws + 667648;          // 16*512*132
  A.WgP  = ws + 1748992;
  A.qkvP = ws + 1849344;
  A.outP = ws + 2026752;
  A.ff1P = ws + 2079024;
  A.ff2P = ws + 2890032;
  A.WspP = ws + 3701040;
  A.Wp1P = ws + 3717936;
  A.Wp2P = ws + 3734832;         // end 3,751,728 floats (~14.3 MB)
  A.outp = (float*)d_out;

  void* kargs[] = { (void*)&A };
  hipError_t err = hipLaunchCooperativeKernel((const void*)persist, dim3(256), dim3(256), kargs, 0, stream);
  if (err == hipSuccess) return;

  // ---------- fallback: per-phase launches ----------
  dim3 B(256);
  g_pack<<<dim3(256), B, 0, stream>>>(A);
  auto enc = [&](){
    for (int l=0;l<3;l++){
      g_qkv  <<<dim3(112), B, 0, stream>>>(A, l);
      g_attn <<<dim3(256), B, 0, stream>>>(A);
      g_oproj<<<dim3(32),  B, 0, stream>>>(A, l);
      g_ln   <<<dim3(64),  B, 0, stream>>>(A, A.ln1_s+l*Dd, A.ln1_b+l*Dd, 0, l);
      g_ff   <<<dim3(256), B, 0, stream>>>(A, l);
      g_ln   <<<dim3(64),  B, 0, stream>>>(A, A.ln2_s+l*Dd, A.ln2_b+l*Dd, 1, l);
    }
  };
  g_gates<<<dim3(256), B, 0, stream>>>(A, 0, 0, 0, 1);
  enc();
  for (int t=0;t<20;t++){
    g_proj <<<dim3(32),  B, 0, stream>>>(A);
    g_gates<<<dim3(256), B, 0, stream>>>(A, 0, t, 0, 0);
    enc();
  }
  for (int p=0;p<10;p++){
    g_proj<<<dim3(32), B, 0, stream>>>(A);
    g_mlp <<<dim3(32), B, 0, stream>>>(A, A.Sh, A.Wp1P, A.b_p1, A.X1);
    g_mlp <<<dim3(32), B, 0, stream>>>(A, A.X1, A.Wp2P, A.b_p2, A.X2);
    g_pout<<<dim3(64), B, 0, stream>>>(A, p);
    if (p < 9){
      g_gates<<<dim3(256), B, 0, stream>>>(A, 1, 0, p, 0);
      enc();
    }
  }
}

// Round 5
// 18852.664 us; speedup vs baseline: 1.7348x; 1.7348x over previous
//
#include <hip/hip_runtime.h>
#include <hip/hip_cooperative_groups.h>

namespace cg = cooperative_groups;

// rnn_phy R5. R4's coop launch was silently rejected (zeros + clean sync => no kernel ran).
// R5: identical row-local architecture; error-checked hipLaunchCooperativeKernel with a
// per-phase-kernel fallback built from the SAME phase functions. Coop path de-risked:
// R3-style attention (16-row items, fewer VGPRs), no exotic waitcnt builtin, fixed ph_oln bug.
// Cross-block data (Q/K/V/O) via relaxed SYSTEM-scope atomics (sc0/sc1, coherent at L3,
// no L2 flush); flush-free monotonic barrier; one real grid.sync after weight packing.

#define Dd 130
#define DP 132
#define Hh 128
#define FFf 2048

struct Args {
  const float *Tracks,*W_emb,*b_emb,*W_ih,*W_hh,*b_ih,*b_hh;
  const float *qkv_w,*qkv_b,*out_w,*out_b,*ff1_w,*ff1_b,*ff2_w,*ff2_b;
  const float *ln1_s,*ln1_b,*ln2_s,*ln2_b;
  const float *W_sp,*b_sp,*W_p1,*b_p1,*W_p2,*b_p2,*W_pl,*b_pl;
  float *X,*Q,*Kb,*V,*O,*Sh,*C,*X1,*X2;
  float *qkvP,*outP,*ff1P,*WspP;
  unsigned *flags;
  float *outp;
};

__device__ __forceinline__ float sigm(float x){ return 1.f/(1.f+__expf(-x)); }
__device__ __forceinline__ float dot4(float4 a, float4 b){ return a.x*b.x+a.y*b.y+a.z*b.z+a.w*b.w; }

__device__ __forceinline__ float cload(const float* p){
  return __hip_atomic_load(p, __ATOMIC_RELAXED, __HIP_MEMORY_SCOPE_SYSTEM);
}
__device__ __forceinline__ void cstore(float* p, float v){
  __hip_atomic_store(p, v, __ATOMIC_RELAXED, __HIP_MEMORY_SCOPE_SYSTEM);
}

// flush-free grid barrier: monotonic counter. __syncthreads drains each wave's vmcnt
// (compiler-emitted s_waitcnt vmcnt(0) before s_barrier), so all coherent stores are at the
// coherence point before thread 0 arrives. Guard valve only trips if fundamentally broken.
__device__ void lbar(unsigned* cnt, unsigned target){
  __syncthreads();
  if (threadIdx.x==0){
    __hip_atomic_fetch_add(cnt, 1u, __ATOMIC_RELAXED, __HIP_MEMORY_SCOPE_SYSTEM);
    int guard=0;
    while (__hip_atomic_load(cnt, __ATOMIC_RELAXED, __HIP_MEMORY_SCOPE_SYSTEM) < target){
      __builtin_amdgcn_s_sleep(4);
      if (++guard > (1<<18)) break;
    }
  }
  __syncthreads();
}

// ---- weight packing ----
__device__ void ph_pack(const Args& a){
  int gid = blockIdx.x*256 + threadIdx.x, gsz = 256*256;
  for (int idx=gid; idx<3*392*132; idx+=gsz){
    int j=idx%132, row=(idx/132)%392, l=idx/(132*392);
    a.qkvP[idx] = (row<390 && j<130)? a.qkv_w[(l*390+row)*130+j] : 0.f;
  }
  for (int idx=gid; idx<3*130*132; idx+=gsz){
    int j=idx%132, row=(idx/132)%130, l=idx/(132*130);
    a.outP[idx] = (j<130)? a.out_w[(l*130+row)*130+j] : 0.f;
  }
  for (int idx=gid; idx<3*2048*132; idx+=gsz){
    int j=idx%132, row=(idx/132)%2048, l=idx/(132*2048);
    a.ff1P[idx] = (j<130)? a.ff1_w[(l*2048+row)*130+j] : 0.f;
  }
  for (int idx=gid; idx<128*132; idx+=gsz){
    int j=idx%132, row=idx/132;
    a.WspP[idx] = (j<130)? a.W_sp[row*130+j] : 0.f;
  }
  if (gid==0) a.flags[0] = 0u;
}

// ---- LSTM + embedding, rows 2b,2b+1 ----
__device__ void ph_lstm(const Args& a, float* sm, int b, int xin_mode, int tstep, int p, int zero){
  int r0=2*b, tid=threadIdx.x;
  float* xe  = sm;        // [2][64]
  float* xh  = sm+128;    // [2][128]
  float* xin = sm+384;    // [2][4]
  float* graw= sm+392;    // [2][512]
  if (tid<8){ int r=tid>>2, j=tid&3;
    xin[tid] = (xin_mode==0)? a.Tracks[((r0+r)*20+tstep)*5+1+j] : a.outp[(r0+r)*40+p*4+j]; }
  { int r=tid>>7, u=tid&127;
    xh[r*128+u] = zero? 0.f : a.Sh[(r0+r)*Hh+u]; }
  __syncthreads();
  if (tid<128){ int r=tid>>6, e=tid&63;
    float s=a.b_emb[e];
    #pragma unroll
    for(int j=0;j<4;j++) s+=xin[r*4+j]*a.W_emb[e*4+j];
    xe[r*64+e]=s; }
  __syncthreads();
  const float4* xe0=(const float4*)xe;   const float4* xe1=(const float4*)(xe+64);
  const float4* xh0=(const float4*)xh;   const float4* xh1=(const float4*)(xh+128);
  for (int g2=0; g2<2; g2++){
    int gr = tid + g2*256;
    float acc0=0.f, acc1=0.f;
    const float4* wi=(const float4*)(a.W_ih + gr*64);
    const float4* wh=(const float4*)(a.W_hh + gr*128);
    #pragma unroll 4
    for(int j=0;j<16;j++){ float4 w=wi[j]; acc0+=dot4(w,xe0[j]); acc1+=dot4(w,xe1[j]); }
    #pragma unroll 4
    for(int j=0;j<32;j++){ float4 w=wh[j]; acc0+=dot4(w,xh0[j]); acc1+=dot4(w,xh1[j]); }
    float bb=a.b_ih[gr]+a.b_hh[gr];
    graw[gr]=acc0+bb; graw[512+gr]=acc1+bb;
  }
  __syncthreads();
  { int r=tid>>7, u=tid&127, rr=r0+r;
    float* g_=graw+r*512;
    float gi=g_[u], gf=g_[128+u], gg=g_[256+u], go=g_[384+u];
    float cp = zero? 0.f : a.C[rr*Hh+u];
    float c2 = sigm(gf)*cp + sigm(gi)*tanhf(gg);
    a.C[rr*Hh+u]=c2;
    a.X[rr*DP+u]=sigm(go)*tanhf(c2);
    if (u<2){ a.X[rr*DP+128+u]=xin[r*4+u]; a.X[rr*DP+130+u]=0.f; }
  }
  __syncthreads();
}

// ---- Sh = X @ W_sp^T + b_sp ----
__device__ void ph_proj(const Args& a, float* sm, int b){
  int r0=2*b, tid=threadIdx.x;
  float* xr=sm;
  if (tid<66) ((float4*)xr)[tid] = ((const float4*)(a.X + r0*DP))[tid];
  __syncthreads();
  int r=tid>>7, c=tid&127;
  const float4* w=(const float4*)(a.WspP + c*132);
  const float4* x4=(const float4*)(xr + r*132);
  float acc=0.f;
  #pragma unroll 3
  for(int j=0;j<33;j++) acc+=dot4(w[j],x4[j]);
  a.Sh[(r0+r)*Hh+c] = acc + a.b_sp[c];
  __syncthreads();
}

// ---- out = relu(in@W^T+b)+in, K=128 ----
__device__ void ph_mlp(const Args& a, float* sm, int b, const float* inp, const float* W, const float* bias, float* outp){
  int r0=2*b, tid=threadIdx.x;
  float* xr=sm;
  if (tid<64) ((float4*)xr)[tid] = ((const float4*)(inp + r0*Hh))[tid];
  __syncthreads();
  int r=tid>>7, c=tid&127;
  const float4* w=(const float4*)(W + c*128);
  const float4* x4=(const float4*)(xr + r*128);
  float acc=0.f;
  #pragma unroll 4
  for(int j=0;j<32;j++) acc+=dot4(w[j],x4[j]);
  outp[(r0+r)*Hh+c] = fmaxf(acc+bias[c],0.f) + xr[r*128+c];
  __syncthreads();
}

// ---- QKV (row-local compute; coherent stores) ----
__device__ void ph_qkv(const Args& a, float* sm, int b, int l){
  int r0=2*b, tid=threadIdx.x;
  float* xr=sm;
  if (tid<66) ((float4*)xr)[tid] = ((const float4*)(a.X + r0*DP))[tid];
  __syncthreads();
  const float* qb=a.qkv_b+l*390;
  for (int jj=tid; jj<780; jj+=256){
    int c=jj>>1, r=jj&1, rr=r0+r;
    const float4* w=(const float4*)(a.qkvP + (l*392+c)*132);
    const float4* x4=(const float4*)(xr + r*132);
    float acc=0.f;
    #pragma unroll 3
    for(int j=0;j<33;j++) acc+=dot4(w[j],x4[j]);
    acc += qb[c];
    if (c<130)      cstore(a.Q +rr*DP+c,       acc);
    else if (c<260) cstore(a.Kb+rr*DP+(c-130), acc);
    else            cstore(a.V +rr*DP+(c-260), acc);
  }
  __syncthreads();
}

// ---- attention: 320 items (16-row tile x head), blocks stride 256; R3-proven structure ----
__device__ void ph_attn(const Args& a, float* sm, int b){
  float* kv=sm;          // 512 x 20
  float* qs=sm+10240;    // 16 x 13
  int tid=threadIdx.x, mg=tid&15, ii=tid>>4;
  const float scale=0.27735009811f;  // 1/sqrt(13)
  for (int item=b; item<320; item+=256){
    int tile=item&31, head=item>>5;
    int r0=tile*16, hc=head*13;
    __syncthreads();
    for (int idx=tid; idx<512*13; idx+=256){ int m=idx/13, d=idx-13*m; kv[m*20+d]=cload(a.Kb+m*DP+hc+d); }
    for (int idx=tid; idx<208; idx+=256){ int r=idx/13, d=idx-13*r; qs[idx]=cload(a.Q+(r0+r)*DP+hc+d); }
    __syncthreads();
    float q[13];
    #pragma unroll
    for(int d=0;d<13;d++) q[d]=qs[ii*13+d]*scale;
    float4 q0={q[0],q[1],q[2],q[3]}, q1={q[4],q[5],q[6],q[7]}, q2={q[8],q[9],q[10],q[11]};
    float s[32], mx=-1e30f;
    #pragma unroll
    for(int k=0;k<32;k++){
      const float* kr=kv+(mg+16*k)*20;
      float v = dot4(q0,*(const float4*)kr) + dot4(q1,*(const float4*)(kr+4))
              + dot4(q2,*(const float4*)(kr+8)) + q[12]*kr[12];
      s[k]=v; mx=fmaxf(mx,v);
    }
    #pragma unroll
    for(int o=8;o>=1;o>>=1) mx=fmaxf(mx,__shfl_xor(mx,o,16));
    float sum=0.f;
    #pragma unroll
    for(int k=0;k<32;k++){ s[k]=__expf(s[k]-mx); sum+=s[k]; }
    #pragma unroll
    for(int o=8;o>=1;o>>=1) sum+=__shfl_xor(sum,o,16);
    float inv=1.f/sum;
    __syncthreads();
    for (int idx=tid; idx<512*13; idx+=256){ int m=idx/13, d=idx-13*m; kv[m*20+d]=cload(a.V+m*DP+hc+d); }
    __syncthreads();
    float o_[13];
    #pragma unroll
    for(int d=0;d<13;d++) o_[d]=0.f;
    #pragma unroll
    for(int k=0;k<32;k++){
      const float* vr=kv+(mg+16*k)*20;
      float pw=s[k];
      float4 v0=*(const float4*)vr, v1=*(const float4*)(vr+4), v2=*(const float4*)(vr+8);
      o_[0]+=pw*v0.x; o_[1]+=pw*v0.y; o_[2] +=pw*v0.z; o_[3] +=pw*v0.w;
      o_[4]+=pw*v1.x; o_[5]+=pw*v1.y; o_[6] +=pw*v1.z; o_[7] +=pw*v1.w;
      o_[8]+=pw*v2.x; o_[9]+=pw*v2.y; o_[10]+=pw*v2.z; o_[11]+=pw*v2.w;
      o_[12]+=pw*vr[12];
    }
    #pragma unroll
    for(int d=0;d<13;d++){
      #pragma unroll
      for(int o=8;o>=1;o>>=1) o_[d]+=__shfl_xor(o_[d],o,16);
    }
    float outv=0.f;
    #pragma unroll
    for(int d=0;d<13;d++) if (mg==d) outv=o_[d];
    if (mg<13) cstore(a.O+(r0+ii)*DP+mg, outv*inv);
  }
  __syncthreads();
}

// ---- oproj + residual + LN1, rows 2b,2b+1 (coherent O reads) ----
__device__ void ph_oln(const Args& a, float* sm, int b, int l){
  int r0=2*b, tid=threadIdx.x;
  float* orow=sm;       // [2][132]
  float* trow=sm+264;   // [2][132]
  float* red1=sm+528;   // [2][64]
  float* red2=sm+656;   // [2][64]
  float* mi  =sm+784;   // mean[2], inv[2]
  for (int idx=tid; idx<264; idx+=256){ int r=idx/132, c=idx-132*r;
    orow[idx] = (c<130)? cload(a.O+(r0+r)*DP+c) : 0.f; }
  __syncthreads();
  const float* ob=a.out_b+l*Dd;
  for (int jj=tid; jj<260; jj+=256){
    int c=jj>>1, r=jj&1;
    const float4* w=(const float4*)(a.outP+(l*130+c)*132);
    const float4* o4=(const float4*)(orow+r*132);
    float acc=0.f;
    #pragma unroll 3
    for(int j=0;j<33;j++) acc+=dot4(w[j],o4[j]);
    trow[r*132+c] = acc + ob[c] + a.X[(r0+r)*DP+c];
  }
  __syncthreads();
  if (tid<128){ int r=tid>>6, ln=tid&63;
    float s1=0.f,s2=0.f;
    for(int c=ln;c<130;c+=64){ float v=trow[r*132+c]; s1+=v; s2+=v*v; }
    red1[r*64+ln]=s1; red2[r*64+ln]=s2; }
  __syncthreads();
  if (tid<2){ float s1=0.f,s2=0.f;
    for(int k=0;k<64;k++){ s1+=red1[tid*64+k]; s2+=red2[tid*64+k]; }
    float m=s1/130.f; mi[tid]=m; mi[2+tid]=rsqrtf(s2/130.f-m*m+1e-5f); }
  __syncthreads();
  const float* ls=a.ln1_s+l*Dd; const float* lb=a.ln1_b+l*Dd;
  for (int jj=tid; jj<260; jj+=256){
    int c=jj>>1, r=jj&1;
    a.X[(r0+r)*DP+c] = (trow[r*132+c]-mi[r])*mi[2+r]*ls[c] + lb[c];
  }
  __syncthreads();
}

// ---- FF1 + FF2 + residual + LN2, rows 2b,2b+1 (fully row-local) ----
__device__ void ph_ff(const Args& a, float* sm, int b, int l){
  int r0=2*b, tid=threadIdx.x;
  float* xr  =sm;        // [2][132]
  float* ys  =sm+264;    // [2][2048]
  float* redc=sm+4360;   // 256
  float* mi  =sm+4616;   // 4
  float* trow=sm+4624;   // [2][132]
  if (tid<66) ((float4*)xr)[tid]=((const float4*)(a.X+r0*DP))[tid];
  __syncthreads();
  const float* b1=a.ff1_b+l*FFf;
  const float4* x0=(const float4*)xr; const float4* x1=(const float4*)(xr+132);
  for (int h=tid; h<2048; h+=256){
    const float4* w=(const float4*)(a.ff1P+(l*2048+h)*132);
    float a0=0.f,a1=0.f;
    #pragma unroll 3
    for(int j=0;j<33;j++){ float4 ww=w[j]; a0+=dot4(ww,x0[j]); a1+=dot4(ww,x1[j]); }
    float bb=b1[h];
    ys[h]=fmaxf(a0+bb,0.f); ys[2048+h]=fmaxf(a1+bb,0.f);
  }
  __syncthreads();
  const float* f2b=a.ff2_b+l*Dd;
  { int c=tid&127, r=tid>>7;
    const float4* w=(const float4*)(a.ff2_w+(l*130+c)*2048);
    const float4* y4=(const float4*)(ys+r*2048);
    float acc=0.f;
    #pragma unroll 4
    for(int k=0;k<512;k++) acc+=dot4(w[k],y4[k]);
    trow[r*132+c]=acc+f2b[c]+xr[r*132+c];
  }
  { int jb=tid>>6, chunk=tid&63;
    int c2=128+(jb>>1), r2=jb&1;
    const float4* w=(const float4*)(a.ff2_w+(l*130+c2)*2048);
    const float4* y4=(const float4*)(ys+r2*2048);
    float acc=0.f;
    #pragma unroll
    for(int k=chunk*8;k<chunk*8+8;k++) acc+=dot4(w[k],y4[k]);
    redc[jb*64+chunk]=acc;
  }
  __syncthreads();
  if (tid<4){ int c2=128+(tid>>1), r2=tid&1;
    float acc=0.f;
    for(int k=0;k<64;k++) acc+=redc[tid*64+k];
    trow[r2*132+c2]=acc+f2b[c2]+xr[r2*132+c2];
  }
  __syncthreads();
  float* red1=sm+4360; float* red2=sm+4488;
  if (tid<128){ int r=tid>>6, ln=tid&63;
    float s1=0.f,s2=0.f;
    for(int c=ln;c<130;c+=64){ float v=trow[r*132+c]; s1+=v; s2+=v*v; }
    red1[r*64+ln]=s1; red2[r*64+ln]=s2; }
  __syncthreads();
  if (tid<2){ float s1=0.f,s2=0.f;
    for(int k=0;k<64;k++){ s1+=red1[tid*64+k]; s2+=red2[tid*64+k]; }
    float m=s1/130.f; mi[tid]=m; mi[2+tid]=rsqrtf(s2/130.f-m*m+1e-5f); }
  __syncthreads();
  const float* ls=a.ln2_s+l*Dd; const float* lb=a.ln2_b+l*Dd;
  for (int jj=tid; jj<260; jj+=256){
    int c=jj>>1, r=jj&1;
    a.X[(r0+r)*DP+c]=(trow[r*132+c]-mi[r])*mi[2+r]*ls[c]+lb[c];
  }
  __syncthreads();
}

// ---- pred head (row-local) ----
__device__ void ph_pout(const Args& a, float* sm, int b, int p){
  int r0=2*b, tid=threadIdx.x;
  float* x2=sm;        // [2][128]
  float* red=sm+256;   // [4][16]
  if (tid<64) ((float4*)x2)[tid]=((const float4*)(a.X2+r0*Hh))[tid];
  __syncthreads();
  if (tid<64){ int jr=tid&3, kc=tid>>2;
    int r=jr>>1, j=jr&1;
    float s=0.f;
    for (int v=kc*8; v<kc*8+8; v++) s += x2[r*128+v]*a.W_pl[j*Hh+v];
    red[jr*16+kc]=s; }
  __syncthreads();
  if (tid<4){ int r=tid>>1, j=tid&1, rr=r0+r;
    float av=a.b_pl[j];
    for(int k=0;k<16;k++) av+=red[tid*16+k];
    float cf0, cf2;
    if (p==0){ cf0=a.Tracks[(rr*20+19)*5+1+j]; cf2=a.Tracks[(rr*20+19)*5+3+j]; }
    else     { cf0=a.outp[rr*40+(p-1)*4+j];    cf2=a.outp[rr*40+(p-1)*4+2+j]; }
    float vv=av*0.1f+cf2;
    float pn=av*0.005f+vv*0.1f+cf0;
    a.outp[rr*40+p*4+j]  =pn;
    a.outp[rr*40+p*4+2+j]=vv;
  }
  __syncthreads();
}

// ================= persistent cooperative kernel =================
__global__ void __launch_bounds__(256,1) persist(Args a){
  cg::grid_group grid = cg::this_grid();
  __shared__ float sm[10688];   // 42,752 B
  int b = blockIdx.x;
  unsigned rnd = 0;

  ph_pack(a);
  grid.sync();   // the ONLY heavy sync: publishes packed weights + zeroed barrier counter

  auto layers = [&](){
    for (int l=0;l<3;l++){
      lbar(a.flags, (++rnd)*256u);
      ph_attn(a, sm, b);
      lbar(a.flags, (++rnd)*256u);
      ph_oln(a, sm, b, l);
      ph_ff (a, sm, b, l);
      if (l<2) ph_qkv(a, sm, b, l+1);
    }
  };

  ph_lstm(a, sm, b, 0, 0, 0, 1);
  ph_qkv (a, sm, b, 0);
  layers();
  for (int t=0;t<20;t++){
    ph_proj(a, sm, b);
    ph_lstm(a, sm, b, 0, t, 0, 0);
    ph_qkv (a, sm, b, 0);
    layers();
  }
  for (int p=0;p<10;p++){
    ph_proj(a, sm, b);
    ph_mlp (a, sm, b, a.Sh, a.W_p1, a.b_p1, a.X1);
    ph_mlp (a, sm, b, a.X1, a.W_p2, a.b_p2, a.X2);
    ph_pout(a, sm, b, p);
    if (p<9){
      ph_lstm(a, sm, b, 1, 0, p, 0);
      ph_qkv (a, sm, b, 0);
      layers();
    }
  }
}

// ================= fallback per-phase kernels (same phase functions) =================
#define OPF_OLNFF 1
#define OPF_PROJ  2
#define OPF_PRED  4
#define OPF_LSTM  8
#define OPF_QKV  16

__global__ __launch_bounds__(256) void g_pack(Args a){ ph_pack(a); }
__global__ __launch_bounds__(256) void g_attn(Args a){ __shared__ float sm[10688]; ph_attn(a, sm, blockIdx.x); }
__global__ __launch_bounds__(256) void g_macro(Args a, int ops, int l, int p, int t, int mode, int zero, int lq){
  __shared__ float sm[4888];
  int b = blockIdx.x;
  if (ops & OPF_OLNFF){ ph_oln(a, sm, b, l); ph_ff(a, sm, b, l); }
  if (ops & OPF_PROJ )  ph_proj(a, sm, b);
  if (ops & OPF_PRED ){ ph_mlp(a, sm, b, a.Sh, a.W_p1, a.b_p1, a.X1);
                        ph_mlp(a, sm, b, a.X1, a.W_p2, a.b_p2, a.X2);
                        ph_pout(a, sm, b, p); }
  if (ops & OPF_LSTM )  ph_lstm(a, sm, b, mode, t, p, zero);
  if (ops & OPF_QKV  )  ph_qkv(a, sm, b, lq);
}

extern "C" void kernel_launch(void* const* d_in, const int* in_sizes, int n_in,
                              void* d_out, int out_size, void* d_ws, size_t ws_size,
                              hipStream_t stream) {
  (void)in_sizes; (void)n_in; (void)out_size; (void)ws_size;
  Args A;
  const float* const* in = (const float* const*)d_in;
  A.Tracks=in[0]; A.W_emb=in[1]; A.b_emb=in[2]; A.W_ih=in[3]; A.W_hh=in[4]; A.b_ih=in[5]; A.b_hh=in[6];
  A.qkv_w=in[7]; A.qkv_b=in[8]; A.out_w=in[9]; A.out_b=in[10];
  A.ff1_w=in[11]; A.ff1_b=in[12]; A.ff2_w=in[13]; A.ff2_b=in[14];
  A.ln1_s=in[15]; A.ln1_b=in[16]; A.ln2_s=in[17]; A.ln2_b=in[18];
  A.W_sp=in[19]; A.b_sp=in[20]; A.W_p1=in[21]; A.b_p1=in[22]; A.W_p2=in[23]; A.b_p2=in[24];
  A.W_pl=in[25]; A.b_pl=in[26];
  float* ws = (float*)d_ws;
  A.X    = ws;                 // 512*132 = 67584
  A.Q    = ws + 67584;
  A.Kb   = ws + 135168;
  A.V    = ws + 202752;
  A.O    = ws + 270336;
  A.Sh   = ws + 337920;        // 512*128
  A.C    = ws + 403456;
  A.X1   = ws + 468992;
  A.X2   = ws + 534528;
  A.qkvP = ws + 600064;        // 3*392*132 = 155232
  A.outP = ws + 755296;        // 3*130*132 = 51480
  A.ff1P = ws + 806776;        // 3*2048*132 = 811008
  A.WspP = ws + 1617784;       // 128*132 = 16896
  A.flags= (unsigned*)(ws + 1634680);
  A.outp = (float*)d_out;

  void* kargs[] = { (void*)&A };
  hipError_t err = hipLaunchCooperativeKernel((const void*)persist, dim3(256), dim3(256), kargs, 0, stream);
  if (err == hipSuccess) return;

  // ---------- fallback: same phases as individual kernels ----------
  dim3 B(256);
  g_pack<<<dim3(256), B, 0, stream>>>(A);
  auto layers = [&](){
    for (int l=0;l<3;l++){
      g_attn<<<dim3(256), B, 0, stream>>>(A);
      int ops = OPF_OLNFF | ((l<2) ? OPF_QKV : 0);
      g_macro<<<dim3(256), B, 0, stream>>>(A, ops, l, 0, 0, 0, 0, l+1);
    }
  };
  g_macro<<<dim3(256), B, 0, stream>>>(A, OPF_LSTM|OPF_QKV, 0, 0, 0, 0, 1, 0);
  layers();
  for (int t=0;t<20;t++){
    g_macro<<<dim3(256), B, 0, stream>>>(A, OPF_PROJ|OPF_LSTM|OPF_QKV, 0, 0, t, 0, 0, 0);
    layers();
  }
  for (int p=0;p<10;p++){
    int ops = OPF_PROJ|OPF_PRED | ((p<9) ? (OPF_LSTM|OPF_QKV) : 0);
    g_macro<<<dim3(256), B, 0, stream>>>(A, ops, 0, p, 0, 1, 0, 0);
    if (p<9) layers();
  }
}